// Round 5
// baseline (219.198 us; speedup 1.0000x reference)
//
#include <hip/hip_runtime.h>

typedef __fp16 fp16x2 __attribute__((ext_vector_type(2)));   // cvt_pkrtz result type
typedef _Float16 half8 __attribute__((ext_vector_type(8)));
typedef float floatx4 __attribute__((ext_vector_type(4)));

namespace {

constexpr int NODES = 512;   // nodes per graph
constexpr int DIM   = 256;   // latent dim
constexpr int BM    = 128;   // block tile (rows and cols)
constexpr int BK    = 32;    // K-step (fp32): row = 128 B = 8 x 16B chunks = 32 banks

union Cvt8 { fp16x2 h2[4]; half8 h8; };

__device__ inline half8 pack8(const float4 f0, const float4 f1) {
  Cvt8 c;
  c.h2[0] = __builtin_amdgcn_cvt_pkrtz(f0.x, f0.y);
  c.h2[1] = __builtin_amdgcn_cvt_pkrtz(f0.z, f0.w);
  c.h2[2] = __builtin_amdgcn_cvt_pkrtz(f1.x, f1.y);
  c.h2[3] = __builtin_amdgcn_cvt_pkrtz(f1.z, f1.w);
  return c.h8;
}

// async 16-B global -> LDS DMA; LDS dest = wave-uniform base + lane*16
__device__ inline void async_ld16(const void* g, void* lds) {
  __builtin_amdgcn_global_load_lds(
      (const __attribute__((address_space(1))) unsigned int*)g,
      (__attribute__((address_space(3))) unsigned int*)lds,
      16, 0, 0);
}

// 1280 blocks = 128 graphs x 10 unique tiles (tn<=tm of a 4x4 tile grid).
// 256 threads = 4 waves; each wave a 64x64 sub-tile via 4x4
// mfma_f32_16x16x32_f16. fp32 staged via global_load_lds, cvt on frag read.
// Symmetric epilogue: transposed float4 store always (covers tile (tm,tn)),
// direct scalar store for off-diagonal (covers tile (tn,tm)).
__global__ __launch_bounds__(256, 4)
void decoder_kernel(const float* __restrict__ z, float* __restrict__ out) {
  __shared__ __align__(16) float As[BM * BK];   // 16 KB
  __shared__ __align__(16) float Bs[BM * BK];   // 16 KB

  const int bid = blockIdx.x;
  // XCD swizzle: a graph's 10 blocks share bid%8 -> one XCD's L2 serves
  // only 16 graphs' z (8.4 MB fp32).
  const int idx = bid >> 3;                 // 0..159
  const int gg  = idx / 10;                 // 0..15
  const int t   = idx - gg * 10;            // 0..9
  const int g   = (bid & 7) + 8 * gg;       // graph id
  const int tn  = (int)((0x3221110000ull >> (4 * t)) & 0xF);
  const int tm  = (int)((0x3323213210ull >> (4 * t)) & 0xF);
  const bool diag = (tn == tm);

  const int tid  = threadIdx.x;
  const int lane = tid & 63;
  const int wave = tid >> 6;
  const int wRow = wave >> 1;
  const int wCol = wave & 1;
  const int lrow = lane & 15;
  const int quad = lane >> 4;

  const float* zA = z + ((size_t)g * NODES + tn * BM) * DIM;
  const float* zB = z + ((size_t)g * NODES + tm * BM) * DIM;

  // staging: instr q covers rows q*8..q*8+7; lane -> (row=lane>>3, chunk)
  // global chunk = (lane&7) ^ row  (XOR swizzle; row stride = 32 banks)
  const int rowl = lane >> 3;               // 0..7
  const int csw  = (lane & 7) ^ rowl;
  const size_t sOff = (size_t)rowl * DIM + csw * 4;   // floats

  floatx4 acc[4][4];
#pragma unroll
  for (int i = 0; i < 4; ++i)
#pragma unroll
    for (int j = 0; j < 4; ++j)
      acc[i][j] = (floatx4){0.f, 0.f, 0.f, 0.f};

  const float4* As4 = reinterpret_cast<const float4*>(As);
  const float4* Bs4 = diag ? As4 : reinterpret_cast<const float4*>(Bs);
  const int c0 = (2 * quad) ^ (lrow & 7);       // swizzled chunk of k quad*8..+3
  const int c1 = (2 * quad + 1) ^ (lrow & 7);   // ... k quad*8+4..+7

  for (int kk = 0; kk < DIM; kk += BK) {
#pragma unroll
    for (int it = 0; it < 4; ++it) {
      const int q = wave * 4 + it;          // 0..15
      async_ld16(zA + (size_t)q * 8 * DIM + kk + sOff, &As[q * 256]);
      if (!diag)
        async_ld16(zB + (size_t)q * 8 * DIM + kk + sOff, &Bs[q * 256]);
    }
    __syncthreads();                        // drains vmcnt

    half8 af[4], bf[4];
#pragma unroll
    for (int i = 0; i < 4; ++i) {
      const int r = wRow * 64 + i * 16 + lrow;
      const float4 lo = As4[r * 8 + c0];
      const float4 hi = As4[r * 8 + c1];
      af[i] = pack8(lo, hi);
    }
#pragma unroll
    for (int j = 0; j < 4; ++j) {
      const int r = wCol * 64 + j * 16 + lrow;
      const float4 lo = Bs4[r * 8 + c0];
      const float4 hi = Bs4[r * 8 + c1];
      bf[j] = pack8(lo, hi);
    }
#pragma unroll
    for (int i = 0; i < 4; ++i)
#pragma unroll
      for (int j = 0; j < 4; ++j)
        acc[i][j] = __builtin_amdgcn_mfma_f32_16x16x32_f16(af[i], bf[j], acc[i][j], 0, 0, 0);
    __syncthreads();
  }

  // ---- epilogue: sigmoid; symmetric stores ----
  float* outg = out + (size_t)g * NODES * NODES;
  const int nB = tn * BM + wRow * 64;
  const int mB = tm * BM + wCol * 64;
#pragma unroll
  for (int i = 0; i < 4; ++i) {
#pragma unroll
    for (int j = 0; j < 4; ++j) {
      const int m  = mB + j * 16 + lrow;
      const int n0 = nB + i * 16 + quad * 4;
      float4 v;
      v.x = __builtin_amdgcn_rcpf(1.0f + __expf(-acc[i][j][0]));
      v.y = __builtin_amdgcn_rcpf(1.0f + __expf(-acc[i][j][1]));
      v.z = __builtin_amdgcn_rcpf(1.0f + __expf(-acc[i][j][2]));
      v.w = __builtin_amdgcn_rcpf(1.0f + __expf(-acc[i][j][3]));
      // transposed store: per-lane 4 consecutive cols -> full 64-B lines
      *reinterpret_cast<float4*>(&outg[(size_t)m * NODES + n0]) = v;
      if (!diag) {
        // direct store covers tile (tn,tm); 16 lanes coalesce per row
        outg[(size_t)(n0 + 0) * NODES + m] = v.x;
        outg[(size_t)(n0 + 1) * NODES + m] = v.y;
        outg[(size_t)(n0 + 2) * NODES + m] = v.z;
        outg[(size_t)(n0 + 3) * NODES + m] = v.w;
      }
    }
  }
}

} // namespace

extern "C" void kernel_launch(void* const* d_in, const int* in_sizes, int n_in,
                              void* d_out, int out_size, void* d_ws, size_t ws_size,
                              hipStream_t stream) {
  const float* z = (const float*)d_in[0];
  float* out = (float*)d_out;
  dim3 grid(128 * 10);   // 10 unique tiles per graph (symmetry)
  dim3 block(256);
  hipLaunchKernelGGL(decoder_kernel, grid, block, 0, stream, z, out);
}